// Round 6
// baseline (529.961 us; speedup 1.0000x reference)
//
#include <hip/hip_runtime.h>
#include <hip/hip_bf16.h>

typedef float  f32x16 __attribute__((ext_vector_type(16)));
typedef float  f32x4v __attribute__((ext_vector_type(4)));
typedef short  bf16x8 __attribute__((ext_vector_type(8)));

#define NFRAG 36
#define FRG_BYTES (NFRAG * 64 * 16)        // 36864
#define W2T_BYTES 4096                     // 64 lanes x 16 f32
#define LDS_BYTES (FRG_BYTES + W2T_BYTES)  // 40960
#define WC_BYTE_OFF LDS_BYTES

#define BLK 256
#define COPY_BLOCKS 192
#define EDGE_BLOCKS 576
#define GRID (COPY_BLOCKS + EDGE_BLOCKS)   // 768 = 3 blocks/CU, all resident
#define EDGE_WAVES (EDGE_BLOCKS * 4)       // 2304

__device__ __forceinline__ float sigf(float v) { return 1.0f / (1.0f + __expf(-v)); }
__device__ __forceinline__ float tanhf_fast(float v) {
    float a = fabsf(v);
    float t = __expf(-2.0f * a);
    float r = (1.0f - t) / (1.0f + t);
    return v < 0.0f ? -r : r;
}
__device__ __forceinline__ unsigned pk(float a, float b) {
    union { __hip_bfloat162 h; unsigned u; } c;
    c.h = __float22bfloat162_rn(make_float2(a, b));
    return c.u;
}
__device__ __forceinline__ void nts(f32x4v v, f32x4v* p) {
    __builtin_nontemporal_store(v, p);
}
__device__ __forceinline__ f32x4v fv(float a, float b, float c, float d) {
    f32x4v r; r.x = a; r.y = b; r.z = c; r.w = d; return r;
}

union FragU { uint4 u4; bf16x8 s8; unsigned u[4]; };

__device__ __forceinline__ f32x16 mfma32(bf16x8 a, bf16x8 b, f32x16 c) {
    return __builtin_amdgcn_mfma_f32_32x32x16_bf16(a, b, c, 0, 0, 0);
}

__device__ __forceinline__ void relayout32(f32x16 v, bool hlo, FragU& o0, FragU& o1) {
    unsigned p0 = pk(v[0], v[1]),   p1 = pk(v[2], v[3]);
    unsigned p2 = pk(v[4], v[5]),   p3 = pk(v[6], v[7]);
    unsigned p4 = pk(v[8], v[9]),   p5 = pk(v[10], v[11]);
    unsigned p6 = pk(v[12], v[13]), p7 = pk(v[14], v[15]);
    unsigned q0 = __shfl_xor(hlo ? p2 : p0, 32, 64);
    unsigned q1 = __shfl_xor(hlo ? p3 : p1, 32, 64);
    unsigned q2 = __shfl_xor(hlo ? p6 : p4, 32, 64);
    unsigned q3 = __shfl_xor(hlo ? p7 : p5, 32, 64);
    o0.u[0] = hlo ? p0 : q0; o0.u[1] = hlo ? p1 : q1;
    o0.u[2] = hlo ? q0 : p2; o0.u[3] = hlo ? q1 : p3;
    o1.u[0] = hlo ? p4 : q2; o1.u[1] = hlo ? p5 : q3;
    o1.u[2] = hlo ? q2 : p6; o1.u[3] = hlo ? q3 : p7;
}

__global__ void winner_k(const int* __restrict__ dst_ids, int* __restrict__ winner, int E) {
    int e = blockIdx.x * 256 + threadIdx.x;
    if (e < E) atomicMax(winner + dst_ids[e], e + 1);
}

__global__ void prep_k(const float* __restrict__ msg_W1, const float* __restrict__ msg_b1,
                       const float* __restrict__ msg_W2, const float* __restrict__ msg_b2,
                       const float* __restrict__ w_ih, const float* __restrict__ b_ih,
                       const float* __restrict__ w_hh, const float* __restrict__ b_hh,
                       const float* __restrict__ Wv, const float* __restrict__ bv,
                       const float* __restrict__ Wo, const float* __restrict__ bo,
                       const float* __restrict__ emb_W1, const float* __restrict__ emb_b1,
                       const float* __restrict__ emb_W2, const float* __restrict__ emb_b2,
                       const float* __restrict__ cls_W1, const float* __restrict__ cls_b1,
                       const float* __restrict__ cls_W2, float* __restrict__ WSf) {
    int t = threadIdx.x;  // one block, 256 threads
    unsigned short* frg = (unsigned short*)WSf;
    float* w2t = (float*)((char*)WSf + FRG_BYTES);
    float* WC  = (float*)((char*)WSf + WC_BYTE_OFF);
    float* bc  = WC + 1024;
    for (int i = t; i < 1024; i += 256) {
        int j = i >> 5, k = i & 31;
        float a = 0.0f;
        for (int o = 0; o < 32; ++o) a += Wo[j * 32 + o] * Wv[o * 32 + k];
        WC[i] = a;
    }
    if (t < 32) {
        float a = bo[t];
        for (int o = 0; o < 32; ++o) a += Wo[t * 32 + o] * bv[o];
        bc[t] = a;
    }
    for (int i = t; i < 1024; i += 256) {
        int l = i >> 4, r = i & 15;
        w2t[i] = cls_W2[(r & 3) + 8 * (r >> 2) + 4 * (l >> 5)];
    }
    __syncthreads();
    for (int idx = t; idx < NFRAG * 512; idx += 256) {
        int f = idx >> 9, l = (idx >> 3) & 63, i = idx & 7;
        int j = l & 31, h = l >> 5;
        int L, c;
        if      (f < 5)  { L = 0; c = f; }
        else if (f < 8)  { L = 1; c = f - 5; }
        else if (f < 13) { L = 2; c = f - 8; }
        else if (f < 18) { L = 3; c = f - 13; }
        else if (f < 21) { L = 4; c = f - 18; }
        else if (f < 24) { L = 5; c = f - 21; }
        else if (f < 27) { L = 6; c = f - 24; }
        else if (f < 30) { L = 7; c = f - 27; }
        else if (f < 33) { L = 8; c = f - 30; }
        else             { L = 9; c = f - 33; }
        int k = 16 * c + 8 * h + i;
        float v = 0.0f;
        switch (L) {
            case 0: v = (k < 67) ? msg_W1[j * 67 + k] : (k == 67 ? msg_b1[j] : 0.0f); break;
            case 1: v = (k < 32) ? msg_W2[j * 32 + k] : (k == 32 ? msg_b2[j] : 0.0f); break;
            case 2: { int jj = 32 + j;
                      v = (k < 32) ? w_ih[jj * 32 + k] : (k < 64) ? w_hh[jj * 32 + k - 32]
                          : (k == 64) ? b_ih[jj] + b_hh[jj] : 0.0f; } break;
            case 3: { int jj = j;
                      v = (k < 32) ? w_ih[jj * 32 + k] : (k < 64) ? w_hh[jj * 32 + k - 32]
                          : (k == 64) ? b_ih[jj] + b_hh[jj] : 0.0f; } break;
            case 4: { int jj = 64 + j;
                      v = (k < 32) ? w_hh[jj * 32 + k] : (k == 32 ? b_hh[jj] : 0.0f); } break;
            case 5: { int jj = 64 + j;
                      v = (k < 32) ? w_ih[jj * 32 + k] : (k == 32 ? b_ih[jj] : 0.0f); } break;
            case 6: v = (k < 32) ? WC[j * 32 + k] : (k == 32 ? bc[j] : 0.0f); break;
            case 7: v = (k < 34) ? emb_W1[j * 34 + k] : (k == 34 ? emb_b1[j] : 0.0f); break;
            case 8: v = (k < 32) ? emb_W2[j * 32 + k] : (k == 32 ? emb_b2[j] : 0.0f); break;
            default: v = (k < 32) ? cls_W1[j * 32 + k] : (k == 32 ? cls_b1[j] : 0.0f); break;
        }
        __hip_bfloat16 hv = __float2bfloat16(v);
        frg[idx] = *(unsigned short*)&hv;
    }
}

__device__ __forceinline__ void compute_group(
    int g, int E, int eI, int h, bool hlo, int lane,
    int e, int dst, int winv, float2 ef, float dtv,
    f32x4v sA, f32x4v sB, f32x4v sC, f32x4v sD,
    f32x4v D0, f32x4v D1, f32x4v D2, f32x4v D3, f32x4v D4, f32x4v D5,
    const unsigned short* frg, const float* w2t, float clsb2,
    float* __restrict__ probs, float* __restrict__ out_mem) {
    int ob = 0;
    asm volatile("" : "+v"(ob));  // keep LDS frag reads inside the loop

#define LF(f) (*(const FragU*)(frg + (((f) * 64 + lane) * 8 + ob))).s8

    f32x4v dA = hlo ? D0 : D1;   // dp[2h]
    f32x4v dB = hlo ? D1 : D2;   // dp[2h+1]
    f32x4v dC = hlo ? D3 : D4;   // dp[4+2h]
    f32x4v dD = hlo ? D4 : D5;   // dp[5+2h]

    FragU Bs0, Bs1, Bd0, Bd1;
    Bs0.u[0] = pk(sA.x, sA.y); Bs0.u[1] = pk(sA.z, sA.w);
    Bs0.u[2] = pk(sB.x, sB.y); Bs0.u[3] = pk(sB.z, sB.w);
    Bs1.u[0] = pk(sC.x, sC.y); Bs1.u[1] = pk(sC.z, sC.w);
    Bs1.u[2] = pk(sD.x, sD.y); Bs1.u[3] = pk(sD.z, sD.w);
    Bd0.u[0] = pk(dA.x, dA.y); Bd0.u[1] = pk(dA.z, dA.w);
    Bd0.u[2] = pk(dB.x, dB.y); Bd0.u[3] = pk(dB.z, dB.w);
    Bd1.u[0] = pk(dC.x, dC.y); Bd1.u[1] = pk(dC.z, dC.w);
    Bd1.u[2] = pk(dD.x, dD.y); Bd1.u[3] = pk(dD.z, dD.w);
    f32x16 dmt;   // dst mem in D layout (exact f32): dp[h], dp[2+h], dp[4+h], dp[6+h]
    dmt[0]=D0.x;  dmt[1]=D0.y;  dmt[2]=D0.z;  dmt[3]=D0.w;
    dmt[4]=D2.x;  dmt[5]=D2.y;  dmt[6]=D2.z;  dmt[7]=D2.w;
    dmt[8]=D3.x;  dmt[9]=D3.y;  dmt[10]=D3.z; dmt[11]=D3.w;
    dmt[12]=D5.x; dmt[13]=D5.y; dmt[14]=D5.z; dmt[15]=D5.w;

    FragU Bbias, Bt1, Bt2;
    Bbias.u[0] = hlo ? 0x00003F80u : 0u; Bbias.u[1] = 0; Bbias.u[2] = 0; Bbias.u[3] = 0;
    Bt1.u[0] = hlo ? pk(ef.x, ef.y) : 0u; Bt1.u[1] = hlo ? pk(dtv, 1.0f) : 0u;
    Bt1.u[2] = 0; Bt1.u[3] = 0;
    Bt2.u[0] = hlo ? pk(ef.x, ef.y) : 0u; Bt2.u[1] = hlo ? pk(1.0f, 0.0f) : 0u;
    Bt2.u[2] = 0; Bt2.u[3] = 0;

    // msg1
    f32x16 c{};
    c = mfma32(LF(0), Bs0.s8, c); c = mfma32(LF(1), Bs1.s8, c);
    c = mfma32(LF(2), Bd0.s8, c); c = mfma32(LF(3), Bd1.s8, c);
    c = mfma32(LF(4), Bt1.s8, c);
#pragma unroll
    for (int r = 0; r < 16; ++r) c[r] = fmaxf(c[r], 0.0f);
    FragU Bh0, Bh1; relayout32(c, hlo, Bh0, Bh1);

    // msg2
    f32x16 cm{};
    cm = mfma32(LF(5), Bh0.s8, cm); cm = mfma32(LF(6), Bh1.s8, cm);
    cm = mfma32(LF(7), Bbias.s8, cm);
    FragU Bm0, Bm1; relayout32(cm, hlo, Bm0, Bm1);

    // attn -> emb1 -> emb2 -> cls
    f32x16 ca{};
    ca = mfma32(LF(24), Bd0.s8, ca); ca = mfma32(LF(25), Bd1.s8, ca);
    ca = mfma32(LF(26), Bbias.s8, ca);
    FragU Ba0, Ba1; relayout32(ca, hlo, Ba0, Ba1);
    f32x16 ce{};
    ce = mfma32(LF(27), Ba0.s8, ce); ce = mfma32(LF(28), Ba1.s8, ce);
    ce = mfma32(LF(29), Bt2.s8, ce);
#pragma unroll
    for (int r = 0; r < 16; ++r) ce[r] = fmaxf(ce[r], 0.0f);
    FragU B10, B11; relayout32(ce, hlo, B10, B11);
    f32x16 c2{};
    c2 = mfma32(LF(30), B10.s8, c2); c2 = mfma32(LF(31), B11.s8, c2);
    c2 = mfma32(LF(32), Bbias.s8, c2);
    FragU B20, B21; relayout32(c2, hlo, B20, B21);
    f32x16 cc{};
    cc = mfma32(LF(33), B20.s8, cc); cc = mfma32(LF(34), B21.s8, cc);
    cc = mfma32(LF(35), Bbias.s8, cc);
    float part = 0.0f;
    {
        const f32x4v* wp = (const f32x4v*)(w2t + (lane * 16 + ob));
#pragma unroll
        for (int q = 0; q < 4; ++q) {
            f32x4v w = wp[q];
#pragma unroll
            for (int i = 0; i < 4; ++i)
                part = fmaf(fmaxf(cc[4 * q + i], 0.0f), w[i], part);
        }
    }
    part += __shfl_xor(part, 32, 64);
    {
        int ee = g * 32 + eI;
        if (hlo && ee < E) probs[ee] = sigf(part + clsb2);
    }

    // GRU
    f32x16 cr{};
    cr = mfma32(LF(13), Bm0.s8, cr); cr = mfma32(LF(14), Bm1.s8, cr);
    cr = mfma32(LF(15), Bd0.s8, cr); cr = mfma32(LF(16), Bd1.s8, cr);
    cr = mfma32(LF(17), Bbias.s8, cr);
    f32x16 ch{};
    ch = mfma32(LF(18), Bd0.s8, ch); ch = mfma32(LF(19), Bd1.s8, ch);
    ch = mfma32(LF(20), Bbias.s8, ch);
    f32x16 cn;
#pragma unroll
    for (int r = 0; r < 16; ++r) cn[r] = sigf(cr[r]) * ch[r];
    cn = mfma32(LF(21), Bm0.s8, cn); cn = mfma32(LF(22), Bm1.s8, cn);
    cn = mfma32(LF(23), Bbias.s8, cn);
    f32x16 cz{};
    cz = mfma32(LF(8), Bm0.s8, cz);  cz = mfma32(LF(9), Bm1.s8, cz);
    cz = mfma32(LF(10), Bd0.s8, cz); cz = mfma32(LF(11), Bd1.s8, cz);
    cz = mfma32(LF(12), Bbias.s8, cz);
    f32x16 uu;
#pragma unroll
    for (int r = 0; r < 16; ++r) {
        float n = tanhf_fast(cn[r]);
        float z = sigf(cz[r]);
        uu[r] = n + z * (dmt[r] - n);
    }
    if (winv == e + 1) {
        f32x4v* orow = (f32x4v*)(out_mem + (size_t)dst * 32);
        nts(fv(uu[0],  uu[1],  uu[2],  uu[3]),  orow + h);
        nts(fv(uu[4],  uu[5],  uu[6],  uu[7]),  orow + 2 + h);
        nts(fv(uu[8],  uu[9],  uu[10], uu[11]), orow + 4 + h);
        nts(fv(uu[12], uu[13], uu[14], uu[15]), orow + 6 + h);
    }
#undef LF
}

__global__ __launch_bounds__(BLK, 3) void tgn_mfma32(
    const int* __restrict__ src_ids, const int* __restrict__ dst_ids,
    const float* __restrict__ edge_feat, const float* __restrict__ delta_t,
    const float* __restrict__ memory, const float* __restrict__ cls_b2,
    const float* __restrict__ WSf, const int* __restrict__ winner,
    float* __restrict__ probs, float* __restrict__ out_mem,
    int E, int N, int ngrp) {
    __shared__ uint4 sbuf[LDS_BYTES / 16];
    int bid = blockIdx.x, tid = threadIdx.x;

    if (bid < COPY_BLOCKS) {  // copy workers: non-winner rows -> out_mem (row/thread)
        const f32x4v* m4 = (const f32x4v*)memory;
        f32x4v* o4 = (f32x4v*)out_mem;
        const int stride = COPY_BLOCKS * BLK;
        for (int row = bid * BLK + tid; row < N; row += 2 * stride) {
            int rowb = row + stride;
            int wa = winner[row];
            int wb = (rowb < N) ? winner[rowb] : 1;
            if (wa == 0) {
                const f32x4v* s = m4 + (size_t)row * 8;
                f32x4v r0=s[0],r1=s[1],r2=s[2],r3=s[3],r4=s[4],r5=s[5],r6=s[6],r7=s[7];
                f32x4v* d = o4 + (size_t)row * 8;
                nts(r0, d+0); nts(r1, d+1); nts(r2, d+2); nts(r3, d+3);
                nts(r4, d+4); nts(r5, d+5); nts(r6, d+6); nts(r7, d+7);
            }
            if (wb == 0) {
                const f32x4v* s = m4 + (size_t)rowb * 8;
                f32x4v r0=s[0],r1=s[1],r2=s[2],r3=s[3],r4=s[4],r5=s[5],r6=s[6],r7=s[7];
                f32x4v* d = o4 + (size_t)rowb * 8;
                nts(r0, d+0); nts(r1, d+1); nts(r2, d+2); nts(r3, d+3);
                nts(r4, d+4); nts(r5, d+5); nts(r6, d+6); nts(r7, d+7);
            }
        }
        return;
    }

    {
        const uint4* s = (const uint4*)WSf;
        for (int i = tid; i < LDS_BYTES / 16; i += BLK) sbuf[i] = s[i];
    }
    __syncthreads();
    const unsigned short* frg = (const unsigned short*)sbuf;
    const float* w2t = (const float*)((const char*)sbuf + FRG_BYTES);

    int wv = tid >> 6, lane = tid & 63;
    int eI = lane & 31, h = lane >> 5;
    bool hlo = (h == 0);
    int ewid = (bid - COPY_BLOCKS) * 4 + wv;
    float clsb2 = cls_b2[0];

#define PREF(P, G) do {                                                              \
    int ee = (G) * 32 + eI; if (ee >= E) ee = E - 1;                                 \
    e##P = ee;                                                                       \
    int sid = src_ids[ee]; dst##P = dst_ids[ee];                                     \
    ef##P = ((const float2*)edge_feat)[ee]; dt##P = delta_t[ee];                     \
    win##P = winner[dst##P];                                                         \
    const f32x4v* sp_ = (const f32x4v*)(memory + (size_t)sid * 32);                  \
    const f32x4v* dp_ = (const f32x4v*)(memory + (size_t)dst##P * 32);               \
    S##P##0 = sp_[2*h]; S##P##1 = sp_[2*h+1]; S##P##2 = sp_[4+2*h]; S##P##3 = sp_[5+2*h]; \
    D##P##0 = dp_[h];   D##P##1 = dp_[1+h];   D##P##2 = dp_[2+h];                    \
    D##P##3 = dp_[4+h]; D##P##4 = dp_[5+h];   D##P##5 = dp_[6+h];                    \
} while (0)

    int g = ewid;
    if (g < ngrp) {
        int eA, dstA, winA; float2 efA; float dtA;
        f32x4v SA0, SA1, SA2, SA3, DA0, DA1, DA2, DA3, DA4, DA5;
        int eB, dstB, winB; float2 efB; float dtB;
        f32x4v SB0, SB1, SB2, SB3, DB0, DB1, DB2, DB3, DB4, DB5;
        PREF(A, g);
        for (;;) {
            int gn = g + EDGE_WAVES;
            { int gp = (gn < ngrp) ? gn : (ngrp - 1); PREF(B, gp); }
            compute_group(g, E, eI, h, hlo, lane, eA, dstA, winA, efA, dtA,
                          SA0, SA1, SA2, SA3, DA0, DA1, DA2, DA3, DA4, DA5,
                          frg, w2t, clsb2, probs, out_mem);
            if (gn >= ngrp) break;
            g = gn;
            gn = g + EDGE_WAVES;
            { int gp = (gn < ngrp) ? gn : (ngrp - 1); PREF(A, gp); }
            compute_group(g, E, eI, h, hlo, lane, eB, dstB, winB, efB, dtB,
                          SB0, SB1, SB2, SB3, DB0, DB1, DB2, DB3, DB4, DB5,
                          frg, w2t, clsb2, probs, out_mem);
            if (gn >= ngrp) break;
            g = gn;
        }
    }
#undef PREF
}

extern "C" void kernel_launch(void* const* d_in, const int* in_sizes, int n_in,
                              void* d_out, int out_size, void* d_ws, size_t ws_size,
                              hipStream_t stream) {
    const int*   src_ids   = (const int*)d_in[0];
    const int*   dst_ids   = (const int*)d_in[1];
    const float* edge_feat = (const float*)d_in[2];
    const float* delta_t   = (const float*)d_in[3];
    const float* memory    = (const float*)d_in[4];
    const float* msg_W1 = (const float*)d_in[5],  *msg_b1 = (const float*)d_in[6];
    const float* msg_W2 = (const float*)d_in[7],  *msg_b2 = (const float*)d_in[8];
    const float* w_ih   = (const float*)d_in[9],  *b_ih   = (const float*)d_in[10];
    const float* w_hh   = (const float*)d_in[11], *b_hh   = (const float*)d_in[12];
    const float* Wv     = (const float*)d_in[13], *bv     = (const float*)d_in[14];
    const float* Wo     = (const float*)d_in[15], *bo     = (const float*)d_in[16];
    const float* emb_W1 = (const float*)d_in[17], *emb_b1 = (const float*)d_in[18];
    const float* emb_W2 = (const float*)d_in[19], *emb_b2 = (const float*)d_in[20];
    const float* cls_W1 = (const float*)d_in[21], *cls_b1 = (const float*)d_in[22];
    const float* cls_W2 = (const float*)d_in[23], *cls_b2 = (const float*)d_in[24];

    int E = in_sizes[0];
    int N = in_sizes[4] / 32;
    int ngrp = (E + 31) / 32;

    int*   winner = (int*)d_ws;
    float* WSf    = (float*)((char*)d_ws + (size_t)N * sizeof(int));
    float* probs  = (float*)d_out;
    float* outmem = probs + E;

    hipMemsetAsync(winner, 0, (size_t)N * sizeof(int), stream);
    winner_k<<<(E + 255) / 256, 256, 0, stream>>>(dst_ids, winner, E);
    prep_k<<<1, 256, 0, stream>>>(msg_W1, msg_b1, msg_W2, msg_b2,
                                  w_ih, b_ih, w_hh, b_hh,
                                  Wv, bv, Wo, bo,
                                  emb_W1, emb_b1, emb_W2, emb_b2,
                                  cls_W1, cls_b1, cls_W2, WSf);
    tgn_mfma32<<<GRID, BLK, 0, stream>>>(src_ids, dst_ids, edge_feat, delta_t,
                                         memory, cls_b2, WSf, winner,
                                         probs, outmem, E, N, ngrp);
}

// Round 7
// 336.814 us; speedup vs baseline: 1.5735x; 1.5735x over previous
//
#include <hip/hip_runtime.h>
#include <hip/hip_bf16.h>

typedef float  f32x16 __attribute__((ext_vector_type(16)));
typedef float  f32x4v __attribute__((ext_vector_type(4)));
typedef short  bf16x8 __attribute__((ext_vector_type(8)));

#define NFRAG 36
#define FRG_BYTES (NFRAG * 64 * 16)        // 36864
#define W2T_BYTES 4096                     // 64 lanes x 16 f32
#define LDS_BYTES (FRG_BYTES + W2T_BYTES)  // 40960 (exactly 4 blocks/CU at 160 KiB)
#define WC_BYTE_OFF LDS_BYTES

#define BLK 256
#define COPY_BLOCKS 256
#define EDGE_BLOCKS 768
#define GRID (COPY_BLOCKS + EDGE_BLOCKS)   // 1024 = 4 blocks/CU, all resident
#define EDGE_WAVES (EDGE_BLOCKS * 4)       // 3072

__device__ __forceinline__ float sigf(float v) { return 1.0f / (1.0f + __expf(-v)); }
__device__ __forceinline__ float tanhf_fast(float v) {
    float a = fabsf(v);
    float t = __expf(-2.0f * a);
    float r = (1.0f - t) / (1.0f + t);
    return v < 0.0f ? -r : r;
}
__device__ __forceinline__ unsigned pk(float a, float b) {
    union { __hip_bfloat162 h; unsigned u; } c;
    c.h = __float22bfloat162_rn(make_float2(a, b));
    return c.u;
}
__device__ __forceinline__ f32x4v fv(float a, float b, float c, float d) {
    f32x4v r; r.x = a; r.y = b; r.z = c; r.w = d; return r;
}

union FragU { uint4 u4; bf16x8 s8; unsigned u[4]; };

__device__ __forceinline__ f32x16 mfma32(bf16x8 a, bf16x8 b, f32x16 c) {
    return __builtin_amdgcn_mfma_f32_32x32x16_bf16(a, b, c, 0, 0, 0);
}

__device__ __forceinline__ void relayout32(f32x16 v, bool hlo, FragU& o0, FragU& o1) {
    unsigned p0 = pk(v[0], v[1]),   p1 = pk(v[2], v[3]);
    unsigned p2 = pk(v[4], v[5]),   p3 = pk(v[6], v[7]);
    unsigned p4 = pk(v[8], v[9]),   p5 = pk(v[10], v[11]);
    unsigned p6 = pk(v[12], v[13]), p7 = pk(v[14], v[15]);
    unsigned q0 = __shfl_xor(hlo ? p2 : p0, 32, 64);
    unsigned q1 = __shfl_xor(hlo ? p3 : p1, 32, 64);
    unsigned q2 = __shfl_xor(hlo ? p6 : p4, 32, 64);
    unsigned q3 = __shfl_xor(hlo ? p7 : p5, 32, 64);
    o0.u[0] = hlo ? p0 : q0; o0.u[1] = hlo ? p1 : q1;
    o0.u[2] = hlo ? q0 : p2; o0.u[3] = hlo ? q1 : p3;
    o1.u[0] = hlo ? p4 : q2; o1.u[1] = hlo ? p5 : q3;
    o1.u[2] = hlo ? q2 : p6; o1.u[3] = hlo ? q3 : p7;
}

__global__ void winner_k(const int* __restrict__ dst_ids, int* __restrict__ winner, int E) {
    int e = blockIdx.x * 256 + threadIdx.x;
    if (e < E) atomicMax(winner + dst_ids[e], e + 1);
}

__global__ void prep_k(const float* __restrict__ msg_W1, const float* __restrict__ msg_b1,
                       const float* __restrict__ msg_W2, const float* __restrict__ msg_b2,
                       const float* __restrict__ w_ih, const float* __restrict__ b_ih,
                       const float* __restrict__ w_hh, const float* __restrict__ b_hh,
                       const float* __restrict__ Wv, const float* __restrict__ bv,
                       const float* __restrict__ Wo, const float* __restrict__ bo,
                       const float* __restrict__ emb_W1, const float* __restrict__ emb_b1,
                       const float* __restrict__ emb_W2, const float* __restrict__ emb_b2,
                       const float* __restrict__ cls_W1, const float* __restrict__ cls_b1,
                       const float* __restrict__ cls_W2, float* __restrict__ WSf) {
    int t = threadIdx.x;  // one block, 256 threads
    unsigned short* frg = (unsigned short*)WSf;
    float* w2t = (float*)((char*)WSf + FRG_BYTES);
    float* WC  = (float*)((char*)WSf + WC_BYTE_OFF);
    float* bc  = WC + 1024;
    for (int i = t; i < 1024; i += 256) {
        int j = i >> 5, k = i & 31;
        float a = 0.0f;
        for (int o = 0; o < 32; ++o) a += Wo[j * 32 + o] * Wv[o * 32 + k];
        WC[i] = a;
    }
    if (t < 32) {
        float a = bo[t];
        for (int o = 0; o < 32; ++o) a += Wo[t * 32 + o] * bv[o];
        bc[t] = a;
    }
    for (int i = t; i < 1024; i += 256) {
        int l = i >> 4, r = i & 15;
        w2t[i] = cls_W2[(r & 3) + 8 * (r >> 2) + 4 * (l >> 5)];
    }
    __syncthreads();
    for (int idx = t; idx < NFRAG * 512; idx += 256) {
        int f = idx >> 9, l = (idx >> 3) & 63, i = idx & 7;
        int j = l & 31, h = l >> 5;
        int L, c;
        if      (f < 5)  { L = 0; c = f; }
        else if (f < 8)  { L = 1; c = f - 5; }
        else if (f < 13) { L = 2; c = f - 8; }
        else if (f < 18) { L = 3; c = f - 13; }
        else if (f < 21) { L = 4; c = f - 18; }
        else if (f < 24) { L = 5; c = f - 21; }
        else if (f < 27) { L = 6; c = f - 24; }
        else if (f < 30) { L = 7; c = f - 27; }
        else if (f < 33) { L = 8; c = f - 30; }
        else             { L = 9; c = f - 33; }
        int k = 16 * c + 8 * h + i;
        float v = 0.0f;
        switch (L) {
            case 0: v = (k < 67) ? msg_W1[j * 67 + k] : (k == 67 ? msg_b1[j] : 0.0f); break;
            case 1: v = (k < 32) ? msg_W2[j * 32 + k] : (k == 32 ? msg_b2[j] : 0.0f); break;
            case 2: { int jj = 32 + j;
                      v = (k < 32) ? w_ih[jj * 32 + k] : (k < 64) ? w_hh[jj * 32 + k - 32]
                          : (k == 64) ? b_ih[jj] + b_hh[jj] : 0.0f; } break;
            case 3: { int jj = j;
                      v = (k < 32) ? w_ih[jj * 32 + k] : (k < 64) ? w_hh[jj * 32 + k - 32]
                          : (k == 64) ? b_ih[jj] + b_hh[jj] : 0.0f; } break;
            case 4: { int jj = 64 + j;
                      v = (k < 32) ? w_hh[jj * 32 + k] : (k == 32 ? b_hh[jj] : 0.0f); } break;
            case 5: { int jj = 64 + j;
                      v = (k < 32) ? w_ih[jj * 32 + k] : (k == 32 ? b_ih[jj] : 0.0f); } break;
            case 6: v = (k < 32) ? WC[j * 32 + k] : (k == 32 ? bc[j] : 0.0f); break;
            case 7: v = (k < 34) ? emb_W1[j * 34 + k] : (k == 34 ? emb_b1[j] : 0.0f); break;
            case 8: v = (k < 32) ? emb_W2[j * 32 + k] : (k == 32 ? emb_b2[j] : 0.0f); break;
            default: v = (k < 32) ? cls_W1[j * 32 + k] : (k == 32 ? cls_b1[j] : 0.0f); break;
        }
        __hip_bfloat16 hv = __float2bfloat16(v);
        frg[idx] = *(unsigned short*)&hv;
    }
}

__device__ __forceinline__ void compute_group(
    int g, int E, int eI, int h, bool hlo, int lane,
    int e, int dst, int winv, float2 ef, float dtv,
    f32x4v sA, f32x4v sB, f32x4v sC, f32x4v sD,
    f32x4v D0, f32x4v D1, f32x4v D2, f32x4v D3, f32x4v D4, f32x4v D5,
    const unsigned short* frg, const float* w2t, float clsb2,
    float* __restrict__ probs, float* __restrict__ out_mem) {
    int ob = 0;
    asm volatile("" : "+v"(ob));  // keep LDS frag reads inside the loop

#define LF(f) (*(const FragU*)(frg + (((f) * 64 + lane) * 8 + ob))).s8

    f32x4v dA = hlo ? D0 : D1;   // dp[2h]
    f32x4v dB = hlo ? D1 : D2;   // dp[2h+1]
    f32x4v dC = hlo ? D3 : D4;   // dp[4+2h]
    f32x4v dD = hlo ? D4 : D5;   // dp[5+2h]

    FragU Bs0, Bs1, Bd0, Bd1;
    Bs0.u[0] = pk(sA.x, sA.y); Bs0.u[1] = pk(sA.z, sA.w);
    Bs0.u[2] = pk(sB.x, sB.y); Bs0.u[3] = pk(sB.z, sB.w);
    Bs1.u[0] = pk(sC.x, sC.y); Bs1.u[1] = pk(sC.z, sC.w);
    Bs1.u[2] = pk(sD.x, sD.y); Bs1.u[3] = pk(sD.z, sD.w);
    Bd0.u[0] = pk(dA.x, dA.y); Bd0.u[1] = pk(dA.z, dA.w);
    Bd0.u[2] = pk(dB.x, dB.y); Bd0.u[3] = pk(dB.z, dB.w);
    Bd1.u[0] = pk(dC.x, dC.y); Bd1.u[1] = pk(dC.z, dC.w);
    Bd1.u[2] = pk(dD.x, dD.y); Bd1.u[3] = pk(dD.z, dD.w);
    f32x16 dmt;   // dst mem in D layout (exact f32): dp[h], dp[2+h], dp[4+h], dp[6+h]
    dmt[0]=D0.x;  dmt[1]=D0.y;  dmt[2]=D0.z;  dmt[3]=D0.w;
    dmt[4]=D2.x;  dmt[5]=D2.y;  dmt[6]=D2.z;  dmt[7]=D2.w;
    dmt[8]=D3.x;  dmt[9]=D3.y;  dmt[10]=D3.z; dmt[11]=D3.w;
    dmt[12]=D5.x; dmt[13]=D5.y; dmt[14]=D5.z; dmt[15]=D5.w;

    FragU Bbias, Bt1, Bt2;
    Bbias.u[0] = hlo ? 0x00003F80u : 0u; Bbias.u[1] = 0; Bbias.u[2] = 0; Bbias.u[3] = 0;
    Bt1.u[0] = hlo ? pk(ef.x, ef.y) : 0u; Bt1.u[1] = hlo ? pk(dtv, 1.0f) : 0u;
    Bt1.u[2] = 0; Bt1.u[3] = 0;
    Bt2.u[0] = hlo ? pk(ef.x, ef.y) : 0u; Bt2.u[1] = hlo ? pk(1.0f, 0.0f) : 0u;
    Bt2.u[2] = 0; Bt2.u[3] = 0;

    // msg1
    f32x16 c{};
    c = mfma32(LF(0), Bs0.s8, c); c = mfma32(LF(1), Bs1.s8, c);
    c = mfma32(LF(2), Bd0.s8, c); c = mfma32(LF(3), Bd1.s8, c);
    c = mfma32(LF(4), Bt1.s8, c);
#pragma unroll
    for (int r = 0; r < 16; ++r) c[r] = fmaxf(c[r], 0.0f);
    FragU Bh0, Bh1; relayout32(c, hlo, Bh0, Bh1);

    // msg2
    f32x16 cm{};
    cm = mfma32(LF(5), Bh0.s8, cm); cm = mfma32(LF(6), Bh1.s8, cm);
    cm = mfma32(LF(7), Bbias.s8, cm);
    FragU Bm0, Bm1; relayout32(cm, hlo, Bm0, Bm1);

    // attn -> emb1 -> emb2 -> cls
    f32x16 ca{};
    ca = mfma32(LF(24), Bd0.s8, ca); ca = mfma32(LF(25), Bd1.s8, ca);
    ca = mfma32(LF(26), Bbias.s8, ca);
    FragU Ba0, Ba1; relayout32(ca, hlo, Ba0, Ba1);
    f32x16 ce{};
    ce = mfma32(LF(27), Ba0.s8, ce); ce = mfma32(LF(28), Ba1.s8, ce);
    ce = mfma32(LF(29), Bt2.s8, ce);
#pragma unroll
    for (int r = 0; r < 16; ++r) ce[r] = fmaxf(ce[r], 0.0f);
    FragU B10, B11; relayout32(ce, hlo, B10, B11);
    f32x16 c2{};
    c2 = mfma32(LF(30), B10.s8, c2); c2 = mfma32(LF(31), B11.s8, c2);
    c2 = mfma32(LF(32), Bbias.s8, c2);
    FragU B20, B21; relayout32(c2, hlo, B20, B21);
    f32x16 cc{};
    cc = mfma32(LF(33), B20.s8, cc); cc = mfma32(LF(34), B21.s8, cc);
    cc = mfma32(LF(35), Bbias.s8, cc);
    float part = 0.0f;
    {
        const f32x4v* wp = (const f32x4v*)(w2t + (lane * 16 + ob));
#pragma unroll
        for (int q = 0; q < 4; ++q) {
            f32x4v w = wp[q];
#pragma unroll
            for (int i = 0; i < 4; ++i)
                part = fmaf(fmaxf(cc[4 * q + i], 0.0f), w[i], part);
        }
    }
    part += __shfl_xor(part, 32, 64);
    {
        int ee = g * 32 + eI;
        if (hlo && ee < E) probs[ee] = sigf(part + clsb2);
    }

    // GRU
    f32x16 cr{};
    cr = mfma32(LF(13), Bm0.s8, cr); cr = mfma32(LF(14), Bm1.s8, cr);
    cr = mfma32(LF(15), Bd0.s8, cr); cr = mfma32(LF(16), Bd1.s8, cr);
    cr = mfma32(LF(17), Bbias.s8, cr);
    f32x16 ch{};
    ch = mfma32(LF(18), Bd0.s8, ch); ch = mfma32(LF(19), Bd1.s8, ch);
    ch = mfma32(LF(20), Bbias.s8, ch);
    f32x16 cn;
#pragma unroll
    for (int r = 0; r < 16; ++r) cn[r] = sigf(cr[r]) * ch[r];
    cn = mfma32(LF(21), Bm0.s8, cn); cn = mfma32(LF(22), Bm1.s8, cn);
    cn = mfma32(LF(23), Bbias.s8, cn);
    f32x16 cz{};
    cz = mfma32(LF(8), Bm0.s8, cz);  cz = mfma32(LF(9), Bm1.s8, cz);
    cz = mfma32(LF(10), Bd0.s8, cz); cz = mfma32(LF(11), Bd1.s8, cz);
    cz = mfma32(LF(12), Bbias.s8, cz);
    f32x16 uu;
#pragma unroll
    for (int r = 0; r < 16; ++r) {
        float n = tanhf_fast(cn[r]);
        float z = sigf(cz[r]);
        uu[r] = n + z * (dmt[r] - n);
    }
    if (winv == e + 1) {
        f32x4v* orow = (f32x4v*)(out_mem + (size_t)dst * 32);
        orow[h]     = fv(uu[0],  uu[1],  uu[2],  uu[3]);
        orow[2 + h] = fv(uu[4],  uu[5],  uu[6],  uu[7]);
        orow[4 + h] = fv(uu[8],  uu[9],  uu[10], uu[11]);
        orow[6 + h] = fv(uu[12], uu[13], uu[14], uu[15]);
    }
#undef LF
}

__global__ __launch_bounds__(BLK, 4) void tgn_mfma32(
    const int* __restrict__ src_ids, const int* __restrict__ dst_ids,
    const float* __restrict__ edge_feat, const float* __restrict__ delta_t,
    const float* __restrict__ memory, const float* __restrict__ cls_b2,
    const float* __restrict__ WSf, const int* __restrict__ winner,
    float* __restrict__ probs, float* __restrict__ out_mem,
    int E, int N, int ngrp) {
    __shared__ uint4 sbuf[LDS_BYTES / 16];
    int bid = blockIdx.x, tid = threadIdx.x;

    if (bid < COPY_BLOCKS) {
        // copy workers: non-winner rows -> out_mem. Linear float4 grid-stride
        // (lane-contiguous => coalesced; L2 merges the winner-guarded gaps),
        // 4-way unrolled for memory-level parallelism. Normal stores (L2 WB).
        const f32x4v* m4 = (const f32x4v*)memory;
        f32x4v* o4 = (f32x4v*)out_mem;
        const long S = (long)COPY_BLOCKS * BLK;
        const long total4 = (long)N * 8;
        long i0 = (long)bid * BLK + tid;
        for (; i0 + 3 * S < total4; i0 += 4 * S) {
            long i1 = i0 + S, i2 = i0 + 2 * S, i3 = i0 + 3 * S;
            int w0 = winner[i0 >> 3];
            int w1 = winner[i1 >> 3];
            int w2 = winner[i2 >> 3];
            int w3 = winner[i3 >> 3];
            if (w0 == 0) o4[i0] = m4[i0];
            if (w1 == 0) o4[i1] = m4[i1];
            if (w2 == 0) o4[i2] = m4[i2];
            if (w3 == 0) o4[i3] = m4[i3];
        }
        for (; i0 < total4; i0 += S) {
            if (winner[i0 >> 3] == 0) o4[i0] = m4[i0];
        }
        return;
    }

    {
        const uint4* s = (const uint4*)WSf;
        for (int i = tid; i < LDS_BYTES / 16; i += BLK) sbuf[i] = s[i];
    }
    __syncthreads();
    const unsigned short* frg = (const unsigned short*)sbuf;
    const float* w2t = (const float*)((const char*)sbuf + FRG_BYTES);

    int wv = tid >> 6, lane = tid & 63;
    int eI = lane & 31, h = lane >> 5;
    bool hlo = (h == 0);
    int ewid = (bid - COPY_BLOCKS) * 4 + wv;
    float clsb2 = cls_b2[0];

#define PREF(P, G) do {                                                              \
    int ee = (G) * 32 + eI; if (ee >= E) ee = E - 1;                                 \
    e##P = ee;                                                                       \
    int sid = src_ids[ee]; dst##P = dst_ids[ee];                                     \
    ef##P = ((const float2*)edge_feat)[ee]; dt##P = delta_t[ee];                     \
    win##P = winner[dst##P];                                                         \
    const f32x4v* sp_ = (const f32x4v*)(memory + (size_t)sid * 32);                  \
    const f32x4v* dp_ = (const f32x4v*)(memory + (size_t)dst##P * 32);               \
    S##P##0 = sp_[2*h]; S##P##1 = sp_[2*h+1]; S##P##2 = sp_[4+2*h]; S##P##3 = sp_[5+2*h]; \
    D##P##0 = dp_[h];   D##P##1 = dp_[1+h];   D##P##2 = dp_[2+h];                    \
    D##P##3 = dp_[4+h]; D##P##4 = dp_[5+h];   D##P##5 = dp_[6+h];                    \
} while (0)

    int g = ewid;
    if (g < ngrp) {
        int eA, dstA, winA; float2 efA; float dtA;
        f32x4v SA0, SA1, SA2, SA3, DA0, DA1, DA2, DA3, DA4, DA5;
        int eB, dstB, winB; float2 efB; float dtB;
        f32x4v SB0, SB1, SB2, SB3, DB0, DB1, DB2, DB3, DB4, DB5;
        PREF(A, g);
        for (;;) {
            int gn = g + EDGE_WAVES;
            { int gp = (gn < ngrp) ? gn : (ngrp - 1); PREF(B, gp); }
            compute_group(g, E, eI, h, hlo, lane, eA, dstA, winA, efA, dtA,
                          SA0, SA1, SA2, SA3, DA0, DA1, DA2, DA3, DA4, DA5,
                          frg, w2t, clsb2, probs, out_mem);
            if (gn >= ngrp) break;
            g = gn;
            gn = g + EDGE_WAVES;
            { int gp = (gn < ngrp) ? gn : (ngrp - 1); PREF(A, gp); }
            compute_group(g, E, eI, h, hlo, lane, eB, dstB, winB, efB, dtB,
                          SB0, SB1, SB2, SB3, DB0, DB1, DB2, DB3, DB4, DB5,
                          frg, w2t, clsb2, probs, out_mem);
            if (gn >= ngrp) break;
            g = gn;
        }
    }
#undef PREF
}

extern "C" void kernel_launch(void* const* d_in, const int* in_sizes, int n_in,
                              void* d_out, int out_size, void* d_ws, size_t ws_size,
                              hipStream_t stream) {
    const int*   src_ids   = (const int*)d_in[0];
    const int*   dst_ids   = (const int*)d_in[1];
    const float* edge_feat = (const float*)d_in[2];
    const float* delta_t   = (const float*)d_in[3];
    const float* memory    = (const float*)d_in[4];
    const float* msg_W1 = (const float*)d_in[5],  *msg_b1 = (const float*)d_in[6];
    const float* msg_W2 = (const float*)d_in[7],  *msg_b2 = (const float*)d_in[8];
    const float* w_ih   = (const float*)d_in[9],  *b_ih   = (const float*)d_in[10];
    const float* w_hh   = (const float*)d_in[11], *b_hh   = (const float*)d_in[12];
    const float* Wv     = (const float*)d_in[13], *bv     = (const float*)d_in[14];
    const float* Wo     = (const float*)d_in[15], *bo     = (const float*)d_in[16];
    const float* emb_W1 = (const float*)d_in[17], *emb_b1 = (const float*)d_in[18];
    const float* emb_W2 = (const float*)d_in[19], *emb_b2 = (const float*)d_in[20];
    const float* cls_W1 = (const float*)d_in[21], *cls_b1 = (const float*)d_in[22];
    const float* cls_W2 = (const float*)d_in[23], *cls_b2 = (const float*)d_in[24];

    int E = in_sizes[0];
    int N = in_sizes[4] / 32;
    int ngrp = (E + 31) / 32;

    int*   winner = (int*)d_ws;
    float* WSf    = (float*)((char*)d_ws + (size_t)N * sizeof(int));
    float* probs  = (float*)d_out;
    float* outmem = probs + E;

    hipMemsetAsync(winner, 0, (size_t)N * sizeof(int), stream);
    winner_k<<<(E + 255) / 256, 256, 0, stream>>>(dst_ids, winner, E);
    prep_k<<<1, 256, 0, stream>>>(msg_W1, msg_b1, msg_W2, msg_b2,
                                  w_ih, b_ih, w_hh, b_hh,
                                  Wv, bv, Wo, bo,
                                  emb_W1, emb_b1, emb_W2, emb_b2,
                                  cls_W1, cls_b1, cls_W2, WSf);
    tgn_mfma32<<<GRID, BLK, 0, stream>>>(src_ids, dst_ids, edge_feat, delta_t,
                                         memory, cls_b2, WSf, winner,
                                         probs, outmem, E, N, ngrp);
}

// Round 8
// 293.533 us; speedup vs baseline: 1.8055x; 1.1474x over previous
//
#include <hip/hip_runtime.h>
#include <hip/hip_bf16.h>

typedef float  f32x4v __attribute__((ext_vector_type(4)));
typedef short  bf16x8 __attribute__((ext_vector_type(8)));

#define NFRAG   26
#define TB_F32  512                            // 16 tables x 32 f32
#define FRG_U16 (NFRAG*512)                    // 26 frags x 64 lanes x 8 bf16
#define SHARE_BYTES (TB_F32*4 + FRG_U16*2)     // 28672 B staged to LDS
#define SHARE_U4 (SHARE_BYTES/16)              // 1792 uint4
#define XPK_STRIDE 20                          // u32 stride per edge row (bank spread)
#define SM_F32 (SHARE_BYTES/4 + 4*16*XPK_STRIDE)  // 8448 floats = 33792 B
#define WC_OFF 7168                            // WC scratch offset in WS floats

#define BLK 256
#define COPY_BLOCKS 256
#define EDGE_BLOCKS 768
#define GRID (COPY_BLOCKS + EDGE_BLOCKS)       // 1024 = 4 blocks/CU resident
#define EDGE_WAVES (EDGE_BLOCKS * 4)           // 3072

#define MFMA(a,b,c) __builtin_amdgcn_mfma_f32_16x16x32_bf16(a,b,c,0,0,0)

__device__ __forceinline__ float sigf(float v) { return 1.0f / (1.0f + __expf(-v)); }
__device__ __forceinline__ float tanhf_fast(float v) {
    float a = fabsf(v);
    float t = __expf(-2.0f * a);
    float r = (1.0f - t) / (1.0f + t);
    return v < 0.0f ? -r : r;
}
__device__ __forceinline__ unsigned pk(float a, float b) {   // bf16(a) lo | bf16(b) hi
    union { __hip_bfloat162 h; unsigned u; } c;
    c.h = __float22bfloat162_rn(make_float2(a, b));
    return c.u;
}

union FragU { uint4 u4; bf16x8 s8; unsigned u[4]; };

__device__ __forceinline__ bf16x8 ldfrag(const unsigned short* frg, int idx_u16) {
    FragU c; c.u4 = *(const uint4*)(frg + idx_u16); return c.s8;
}
__device__ __forceinline__ f32x4v tbl(const float* tb, int idx_f32) {
    return *(const f32x4v*)(tb + idx_f32);
}
// D(2 tiles, f32) -> next layer's B fragment via per-wave LDS bounce (R3-verified).
__device__ __forceinline__ bf16x8 relayout(f32x4v h0, f32x4v h1, unsigned* xw, int eI, int g) {
    *(uint2*)(xw + eI * XPK_STRIDE + 2 * g)     = make_uint2(pk(h0[0], h0[1]), pk(h0[2], h0[3]));
    *(uint2*)(xw + eI * XPK_STRIDE + 8 + 2 * g) = make_uint2(pk(h1[0], h1[1]), pk(h1[2], h1[3]));
    FragU c; c.u4 = *(const uint4*)(xw + eI * XPK_STRIDE + 4 * g);
    return c.s8;
}

__global__ void winner_k(const int* __restrict__ dst_ids, int* __restrict__ winner, int E) {
    int e = blockIdx.x * 256 + threadIdx.x;
    if (e < E) atomicMax(winner + dst_ids[e], e + 1);
}

__global__ void prep_k(const float* __restrict__ msg_W1, const float* __restrict__ msg_b1,
                       const float* __restrict__ msg_W2, const float* __restrict__ msg_b2,
                       const float* __restrict__ w_ih, const float* __restrict__ b_ih,
                       const float* __restrict__ w_hh, const float* __restrict__ b_hh,
                       const float* __restrict__ Wv, const float* __restrict__ bv,
                       const float* __restrict__ Wo, const float* __restrict__ bo,
                       const float* __restrict__ emb_W1, const float* __restrict__ emb_b1,
                       const float* __restrict__ emb_W2, const float* __restrict__ emb_b2,
                       const float* __restrict__ cls_W1, const float* __restrict__ cls_b1,
                       const float* __restrict__ cls_W2, float* __restrict__ WSf) {
    int t = threadIdx.x;  // one block, 256 threads
    float* tb = WSf;
    unsigned short* frg = (unsigned short*)(WSf + TB_F32);
    float* WC = WSf + WC_OFF;  // [32][32] folded Wo@Wv
    if (t < 32) {
        int j = t;
        tb[0*32+j]  = msg_b1[j];
        tb[1*32+j]  = msg_W1[j*67+64];
        tb[2*32+j]  = msg_W1[j*67+65];
        tb[3*32+j]  = msg_W1[j*67+66];
        tb[4*32+j]  = msg_b2[j];
        tb[5*32+j]  = b_ih[32+j] + b_hh[32+j];     // z bias
        tb[6*32+j]  = b_ih[j] + b_hh[j];           // r bias
        tb[7*32+j]  = b_hh[64+j];                  // h_n bias
        tb[8*32+j]  = b_ih[64+j];                  // i_n bias
        float a = bo[j];
        for (int o = 0; o < 32; ++o) a += Wo[j*32+o] * bv[o];
        tb[9*32+j]  = a;                           // folded attn bias
        tb[10*32+j] = emb_b1[j];
        tb[11*32+j] = emb_W1[j*34+32];
        tb[12*32+j] = emb_W1[j*34+33];
        tb[13*32+j] = emb_b2[j];
        tb[14*32+j] = cls_b1[j];
        tb[15*32+j] = cls_W2[j];
    }
    for (int i = t; i < 1024; i += 256) {
        int j = i >> 5, k = i & 31;
        float a = 0.0f;
        for (int o = 0; o < 32; ++o) a += Wo[j*32+o] * Wv[o*32+k];
        WC[i] = a;
    }
    __syncthreads();
    // A-fragment pack: frag f, lane l, elem i -> W[j0 + (l&15)][k0 + 8*(l>>4) + i]
    for (int idx = t; idx < NFRAG * 512; idx += 256) {
        int f = idx >> 9, l = (idx >> 3) & 63, i = idx & 7;
        int r = l & 15, kb = ((l >> 4) << 3) + i;
        const float* P; int j0 = 0, k0 = 0, ld = 32;
        switch (f) {
            case 0:  P = msg_W1; j0 = 0;  k0 = 0;  ld = 67; break;
            case 1:  P = msg_W1; j0 = 0;  k0 = 32; ld = 67; break;
            case 2:  P = msg_W1; j0 = 16; k0 = 0;  ld = 67; break;
            case 3:  P = msg_W1; j0 = 16; k0 = 32; ld = 67; break;
            case 4:  P = msg_W2; j0 = 0;  break;
            case 5:  P = msg_W2; j0 = 16; break;
            case 6:  P = w_ih;   j0 = 32; break;   // z ih jt0
            case 7:  P = w_hh;   j0 = 32; break;   // z hh jt0
            case 8:  P = w_ih;   j0 = 48; break;
            case 9:  P = w_hh;   j0 = 48; break;
            case 10: P = w_ih;   j0 = 0;  break;   // r
            case 11: P = w_hh;   j0 = 0;  break;
            case 12: P = w_ih;   j0 = 16; break;
            case 13: P = w_hh;   j0 = 16; break;
            case 14: P = w_hh;   j0 = 64; break;   // n hh
            case 15: P = w_hh;   j0 = 80; break;
            case 16: P = w_ih;   j0 = 64; break;   // n ih
            case 17: P = w_ih;   j0 = 80; break;
            case 18: P = WC;     j0 = 0;  break;   // folded attn
            case 19: P = WC;     j0 = 16; break;
            case 20: P = emb_W1; j0 = 0;  ld = 34; break;
            case 21: P = emb_W1; j0 = 16; ld = 34; break;
            case 22: P = emb_W2; j0 = 0;  break;
            case 23: P = emb_W2; j0 = 16; break;
            case 24: P = cls_W1; j0 = 0;  break;
            default: P = cls_W1; j0 = 16; break;
        }
        __hip_bfloat16 hv = __float2bfloat16(P[(j0 + r) * ld + k0 + kb]);
        frg[idx] = *(unsigned short*)&hv;
    }
}

__device__ __forceinline__ void compute16(
    int grp, int E, int eI, int g, int lane,
    int e, int dst, int winv, float2 ef, float dtv,
    f32x4v sa, f32x4v sb, f32x4v da, f32x4v db, f32x4v t0, f32x4v t1,
    const float* tb, const unsigned short* frg, unsigned* xw, float clsb2,
    float* __restrict__ probs, float* __restrict__ out_mem) {
    int ob = 0, tbo = 0;
    asm volatile("" : "+v"(ob), "+v"(tbo));  // block LICM of LDS frag/table reads

    FragU Bs, Bd;
    Bs.u[0] = pk(sa[0], sa[1]); Bs.u[1] = pk(sa[2], sa[3]);
    Bs.u[2] = pk(sb[0], sb[1]); Bs.u[3] = pk(sb[2], sb[3]);
    Bd.u[0] = pk(da[0], da[1]); Bd.u[1] = pk(da[2], da[3]);
    Bd.u[2] = pk(db[0], db[1]); Bd.u[3] = pk(db[2], db[3]);
    f32x4v dmt[2]; dmt[0] = t0; dmt[1] = t1;   // dst mem in D layout (exact f32)

    // ---- msg1: relu(W1 @ [sm, dm, ef, dt] + b1) ----
    f32x4v h[2];
#pragma unroll
    for (int jt = 0; jt < 2; ++jt) {
        f32x4v b1v = tbl(tb, 0*32 + jt*16 + 4*g + tbo);
        f32x4v w64 = tbl(tb, 1*32 + jt*16 + 4*g + tbo);
        f32x4v w65 = tbl(tb, 2*32 + jt*16 + 4*g + tbo);
        f32x4v w66 = tbl(tb, 3*32 + jt*16 + 4*g + tbo);
        f32x4v c;
#pragma unroll
        for (int i = 0; i < 4; ++i)
            c[i] = b1v[i] + ef.x * w64[i] + ef.y * w65[i] + dtv * w66[i];
        c = MFMA(ldfrag(frg, (jt*2+1)*512 + lane*8 + ob), Bd.s8, c);
        c = MFMA(ldfrag(frg, (jt*2+0)*512 + lane*8 + ob), Bs.s8, c);
#pragma unroll
        for (int i = 0; i < 4; ++i) c[i] = fmaxf(c[i], 0.0f);
        h[jt] = c;
    }
    bf16x8 Bh = relayout(h[0], h[1], xw, eI, g);

    // ---- msg2 ----
    f32x4v m[2];
#pragma unroll
    for (int jt = 0; jt < 2; ++jt)
        m[jt] = MFMA(ldfrag(frg, (4+jt)*512 + lane*8 + ob), Bh,
                     tbl(tb, 4*32 + jt*16 + 4*g + tbo));
    bf16x8 Bm = relayout(m[0], m[1], xw, eI, g);

    // ---- GRU ----
    f32x4v zz[2], uu[2];
#pragma unroll
    for (int jt = 0; jt < 2; ++jt) {
        f32x4v c = tbl(tb, 5*32 + jt*16 + 4*g + tbo);
        c = MFMA(ldfrag(frg, (7+2*jt)*512 + lane*8 + ob), Bd.s8, c);
        c = MFMA(ldfrag(frg, (6+2*jt)*512 + lane*8 + ob), Bm, c);
#pragma unroll
        for (int i = 0; i < 4; ++i) c[i] = sigf(c[i]);
        zz[jt] = c;
    }
#pragma unroll
    for (int jt = 0; jt < 2; ++jt) {
        f32x4v c = tbl(tb, 6*32 + jt*16 + 4*g + tbo);       // r pre-act
        c = MFMA(ldfrag(frg, (11+2*jt)*512 + lane*8 + ob), Bd.s8, c);
        c = MFMA(ldfrag(frg, (10+2*jt)*512 + lane*8 + ob), Bm, c);
        f32x4v hn = tbl(tb, 7*32 + jt*16 + 4*g + tbo);      // h_n
        hn = MFMA(ldfrag(frg, (14+jt)*512 + lane*8 + ob), Bd.s8, hn);
        f32x4v bin = tbl(tb, 8*32 + jt*16 + 4*g + tbo);
        f32x4v npre;
#pragma unroll
        for (int i = 0; i < 4; ++i) npre[i] = fmaf(sigf(c[i]), hn[i], bin[i]);
        npre = MFMA(ldfrag(frg, (16+jt)*512 + lane*8 + ob), Bm, npre);
#pragma unroll
        for (int i = 0; i < 4; ++i) {
            float n = tanhf_fast(npre[i]);
            uu[jt][i] = n + zz[jt][i] * (dmt[jt][i] - n);
        }
    }
    if (winv == e + 1) {
        f32x4v* orow = (f32x4v*)(out_mem + (size_t)dst * 32);
        orow[g]     = uu[0];
        orow[4 + g] = uu[1];
    }

    // ---- attn (folded) -> emb1 -> emb2 -> cls ----
    f32x4v at[2];
#pragma unroll
    for (int jt = 0; jt < 2; ++jt)
        at[jt] = MFMA(ldfrag(frg, (18+jt)*512 + lane*8 + ob), Bd.s8,
                      tbl(tb, 9*32 + jt*16 + 4*g + tbo));
    bf16x8 Ba = relayout(at[0], at[1], xw, eI, g);
    f32x4v e1v[2];
#pragma unroll
    for (int jt = 0; jt < 2; ++jt) {
        f32x4v b  = tbl(tb, 10*32 + jt*16 + 4*g + tbo);
        f32x4v wa = tbl(tb, 11*32 + jt*16 + 4*g + tbo);
        f32x4v wb = tbl(tb, 12*32 + jt*16 + 4*g + tbo);
        f32x4v c;
#pragma unroll
        for (int i = 0; i < 4; ++i) c[i] = b[i] + ef.x * wa[i] + ef.y * wb[i];
        c = MFMA(ldfrag(frg, (20+jt)*512 + lane*8 + ob), Ba, c);
#pragma unroll
        for (int i = 0; i < 4; ++i) c[i] = fmaxf(c[i], 0.0f);
        e1v[jt] = c;
    }
    bf16x8 B1 = relayout(e1v[0], e1v[1], xw, eI, g);
    f32x4v e2v[2];
#pragma unroll
    for (int jt = 0; jt < 2; ++jt)
        e2v[jt] = MFMA(ldfrag(frg, (22+jt)*512 + lane*8 + ob), B1,
                       tbl(tb, 13*32 + jt*16 + 4*g + tbo));
    bf16x8 B2 = relayout(e2v[0], e2v[1], xw, eI, g);
    float part = 0.0f;
#pragma unroll
    for (int jt = 0; jt < 2; ++jt) {
        f32x4v c = MFMA(ldfrag(frg, (24+jt)*512 + lane*8 + ob), B2,
                        tbl(tb, 14*32 + jt*16 + 4*g + tbo));
        f32x4v w2 = tbl(tb, 15*32 + jt*16 + 4*g + tbo);
#pragma unroll
        for (int i = 0; i < 4; ++i) part = fmaf(fmaxf(c[i], 0.0f), w2[i], part);
    }
    part += __shfl_xor(part, 16);
    part += __shfl_xor(part, 32);
    if (lane < 16) {
        int ee = grp * 16 + eI;
        if (ee < E) probs[ee] = sigf(part + clsb2);
    }
}

__global__ __launch_bounds__(BLK, 4) void tgn_mfma16(
    const int* __restrict__ src_ids, const int* __restrict__ dst_ids,
    const float* __restrict__ edge_feat, const float* __restrict__ delta_t,
    const float* __restrict__ memory, const float* __restrict__ cls_b2,
    const float* __restrict__ WSf, const int* __restrict__ winner,
    float* __restrict__ probs, float* __restrict__ out_mem,
    int E, int N, int ngrp) {
    __shared__ float smem[SM_F32];
    int bid = blockIdx.x, tid = threadIdx.x;

    if (bid < COPY_BLOCKS) {  // copy workers: non-winner rows -> out_mem (R7 pattern)
        const f32x4v* m4 = (const f32x4v*)memory;
        f32x4v* o4 = (f32x4v*)out_mem;
        const long S = (long)COPY_BLOCKS * BLK;
        const long total4 = (long)N * 8;
        long i0 = (long)bid * BLK + tid;
        for (; i0 + 3 * S < total4; i0 += 4 * S) {
            long i1 = i0 + S, i2 = i0 + 2 * S, i3 = i0 + 3 * S;
            int w0 = winner[i0 >> 3];
            int w1 = winner[i1 >> 3];
            int w2 = winner[i2 >> 3];
            int w3 = winner[i3 >> 3];
            if (w0 == 0) o4[i0] = m4[i0];
            if (w1 == 0) o4[i1] = m4[i1];
            if (w2 == 0) o4[i2] = m4[i2];
            if (w3 == 0) o4[i3] = m4[i3];
        }
        for (; i0 < total4; i0 += S) {
            if (winner[i0 >> 3] == 0) o4[i0] = m4[i0];
        }
        return;
    }

    {   // stage tables + A-fragments into LDS
        const uint4* s = (const uint4*)WSf;
        uint4* d = (uint4*)smem;
        for (int i = tid; i < SHARE_U4; i += BLK) d[i] = s[i];
    }
    __syncthreads();
    const float* tb = smem;
    const unsigned short* frg = (const unsigned short*)(smem + TB_F32);
    int wv = tid >> 6, lane = tid & 63;
    int eI = lane & 15, g = lane >> 4;
    unsigned* xw = (unsigned*)(smem + SHARE_BYTES / 4) + wv * (16 * XPK_STRIDE);
    int ewid = (bid - COPY_BLOCKS) * 4 + wv;
    float clsb2 = cls_b2[0];

#define PREF(P, G) do {                                                              \
    int ee = (G) * 16 + eI; if (ee >= E) ee = E - 1;                                 \
    e##P = ee;                                                                       \
    int sid = src_ids[ee]; dst##P = dst_ids[ee];                                     \
    ef##P = ((const float2*)edge_feat)[ee]; dt##P = delta_t[ee];                     \
    win##P = winner[dst##P];                                                         \
    const f32x4v* sp_ = (const f32x4v*)(memory + (size_t)sid * 32);                  \
    const f32x4v* dp_ = (const f32x4v*)(memory + (size_t)dst##P * 32);               \
    S##P##a = sp_[2*g]; S##P##b = sp_[2*g+1];                                        \
    D##P##a = dp_[2*g]; D##P##b = dp_[2*g+1];                                        \
    T##P##0 = dp_[g];   T##P##1 = dp_[4+g];                                          \
} while (0)

    int g0 = ewid;
    if (g0 < ngrp) {
        int eA, dstA, winA; float2 efA; float dtA;
        f32x4v SAa, SAb, DAa, DAb, TA0, TA1;
        int eB, dstB, winB; float2 efB; float dtB;
        f32x4v SBa, SBb, DBa, DBb, TB0, TB1;
        PREF(A, g0);
        for (;;) {
            int gn = g0 + EDGE_WAVES;
            { int gp = (gn < ngrp) ? gn : (ngrp - 1); PREF(B, gp); }
            asm volatile("" ::: "memory");   // pin: B's loads may not sink below
            compute16(g0, E, eI, g, lane, eA, dstA, winA, efA, dtA,
                      SAa, SAb, DAa, DAb, TA0, TA1,
                      tb, frg, xw, clsb2, probs, out_mem);
            if (gn >= ngrp) break;
            g0 = gn;
            gn = g0 + EDGE_WAVES;
            { int gp = (gn < ngrp) ? gn : (ngrp - 1); PREF(A, gp); }
            asm volatile("" ::: "memory");
            compute16(g0, E, eI, g, lane, eB, dstB, winB, efB, dtB,
                      SBa, SBb, DBa, DBb, TB0, TB1,
                      tb, frg, xw, clsb2, probs, out_mem);
            if (gn >= ngrp) break;
            g0 = gn;
        }
    }
#undef PREF
}

extern "C" void kernel_launch(void* const* d_in, const int* in_sizes, int n_in,
                              void* d_out, int out_size, void* d_ws, size_t ws_size,
                              hipStream_t stream) {
    const int*   src_ids   = (const int*)d_in[0];
    const int*   dst_ids   = (const int*)d_in[1];
    const float* edge_feat = (const float*)d_in[2];
    const float* delta_t   = (const float*)d_in[3];
    const float* memory    = (const float*)d_in[4];
    const float* msg_W1 = (const float*)d_in[5],  *msg_b1 = (const float*)d_in[6];
    const float* msg_W2 = (const float*)d_in[7],  *msg_b2 = (const float*)d_in[8];
    const float* w_ih   = (const float*)d_in[9],  *b_ih   = (const float*)d_in[10];
    const float* w_hh   = (const float*)d_in[11], *b_hh   = (const float*)d_in[12];
    const float* Wv     = (const float*)d_in[13], *bv     = (const float*)d_in[14];
    const float* Wo     = (const float*)d_in[15], *bo     = (const float*)d_in[16];
    const float* emb_W1 = (const float*)d_in[17], *emb_b1 = (const float*)d_in[18];
    const float* emb_W2 = (const float*)d_in[19], *emb_b2 = (const float*)d_in[20];
    const float* cls_W1 = (const float*)d_in[21], *cls_b1 = (const float*)d_in[22];
    const float* cls_W2 = (const float*)d_in[23], *cls_b2 = (const float*)d_in[24];

    int E = in_sizes[0];
    int N = in_sizes[4] / 32;
    int ngrp = (E + 15) / 16;

    int*   winner = (int*)d_ws;
    float* WSf    = (float*)((char*)d_ws + (size_t)N * sizeof(int));
    float* probs  = (float*)d_out;
    float* outmem = probs + E;

    hipMemsetAsync(winner, 0, (size_t)N * sizeof(int), stream);
    winner_k<<<(E + 255) / 256, 256, 0, stream>>>(dst_ids, winner, E);
    prep_k<<<1, 256, 0, stream>>>(msg_W1, msg_b1, msg_W2, msg_b2,
                                  w_ih, b_ih, w_hh, b_hh,
                                  Wv, bv, Wo, bo,
                                  emb_W1, emb_b1, emb_W2, emb_b2,
                                  cls_W1, cls_b1, cls_W2, WSf);
    tgn_mfma16<<<GRID, BLK, 0, stream>>>(src_ids, dst_ids, edge_feat, delta_t,
                                         memory, cls_b2, WSf, winner,
                                         probs, outmem, E, N, ngrp);
}